// Round 3
// baseline (2350.174 us; speedup 1.0000x reference)
//
#include <hip/hip_runtime.h>
#include <hip/hip_bf16.h>
#include <math.h>

#define DEVI __device__ __forceinline__

typedef __attribute__((ext_vector_type(4))) float f32x4;
typedef __attribute__((ext_vector_type(8))) short s16x8;
typedef __attribute__((ext_vector_type(4))) unsigned int u32x4;

DEVI float bf2f(ushort u){ union{unsigned int i; float f;} x; x.i = ((unsigned int)u)<<16; return x.f; }
DEVI ushort f2bf(float f){ union{float f; unsigned int i;} x; x.f = f;
  unsigned int r = x.i + 0x7fffu + ((x.i>>16)&1u); return (ushort)(r>>16); }

// ---------------- fp32 -> bf16 convert, 4 elems/thread ----------------
__global__ __launch_bounds__(256) void cvt_bf16(const float* __restrict__ in, ushort* __restrict__ out){
  int i = blockIdx.x*256 + threadIdx.x;
  float4 v = ((const float4*)in)[i];
  ushort4 o; o.x = f2bf(v.x); o.y = f2bf(v.y); o.z = f2bf(v.z); o.w = f2bf(v.w);
  ((ushort4*)out)[i] = o;
}

// ---------------- bf16 MFMA GEMM: C[M,N] = A[M,K] * B[N,K]^T ----------------
DEVI void gl_lds16(const ushort* g, ushort* l){
  __builtin_amdgcn_global_load_lds((const __attribute__((address_space(1))) void*)g,
                                   (__attribute__((address_space(3))) void*)l, 16, 0, 0);
}

template<int BF16_OUT>
__global__ __launch_bounds__(256, 2) void gemm_bt(const ushort* __restrict__ A,
                                                  const ushort* __restrict__ B,
                                                  void* __restrict__ Cv,
                                                  int M, int N, int K){
  __shared__ ushort As[128*32];
  __shared__ ushort Bs[128*32];
  const int nb = N >> 7;
  const int tile_m = (blockIdx.x / nb) << 7;
  const int tile_n = (blockIdx.x % nb) << 7;
  const int tid  = threadIdx.x;
  const int w    = tid >> 6;
  const int lane = tid & 63;

  const int ca = w*2;
  const long rowA = tile_m + ca*16 + (lane>>2);
  const long rowB = tile_n + ca*16 + (lane>>2);
  const int  colE = (lane&3)*8;
  const ushort* pA0 = A + rowA*(long)K + colE;
  const ushort* pA1 = pA0 + 16l*K;
  const ushort* pB0 = B + rowB*(long)K + colE;
  const ushort* pB1 = pB0 + 16l*K;
  ushort* lA0 = As + ca*512;
  ushort* lA1 = As + ca*512 + 512;
  ushort* lB0 = Bs + ca*512;
  ushort* lB1 = Bs + ca*512 + 512;

  const int wr = (w>>1)<<6;
  const int wc = (w&1)<<6;
  const int fr = lane & 15;
  const int fk = (lane>>4)<<3;

  f32x4 acc[4][4];
  #pragma unroll
  for (int i=0;i<4;i++)
    #pragma unroll
    for (int j=0;j<4;j++) acc[i][j] = (f32x4){0.f,0.f,0.f,0.f};

  for (int k0 = 0; k0 < K; k0 += 32){
    __syncthreads();
    gl_lds16(pA0, lA0);
    gl_lds16(pA1, lA1);
    gl_lds16(pB0, lB0);
    gl_lds16(pB1, lB1);
    __syncthreads();
    s16x8 af[4], bfr[4];
    #pragma unroll
    for (int t=0;t<4;t++){
      af[t]  = *(const s16x8*)(As + (wr + t*16 + fr)*32 + fk);
      bfr[t] = *(const s16x8*)(Bs + (wc + t*16 + fr)*32 + fk);
    }
    #pragma unroll
    for (int mt=0;mt<4;mt++)
      #pragma unroll
      for (int nt=0;nt<4;nt++)
        acc[mt][nt] = __builtin_amdgcn_mfma_f32_16x16x32_bf16(af[mt], bfr[nt], acc[mt][nt], 0, 0, 0);
    pA0 += 32; pA1 += 32; pB0 += 32; pB1 += 32;
  }

  const int crow = tile_m + wr + ((lane>>4)<<2);
  const int ccol = tile_n + wc + (lane&15);
  if (BF16_OUT){
    ushort* C = (ushort*)Cv;
    #pragma unroll
    for (int mt=0;mt<4;mt++)
      #pragma unroll
      for (int r=0;r<4;r++){
        long row = crow + mt*16 + r;
        #pragma unroll
        for (int nt=0;nt<4;nt++)
          C[row*(long)N + ccol + nt*16] = f2bf(acc[mt][nt][r]);
      }
  } else {
    float* C = (float*)Cv;
    #pragma unroll
    for (int mt=0;mt<4;mt++)
      #pragma unroll
      for (int r=0;r<4;r++){
        long row = crow + mt*16 + r;
        #pragma unroll
        for (int nt=0;nt<4;nt++)
          C[row*(long)N + ccol + nt*16] = acc[mt][nt][r];
      }
  }
}

// ---------------- beta / log-decay projection (fp32 precise) ----------------
__global__ __launch_bounds__(256) void proj_ba(const float* __restrict__ X,
    const float* __restrict__ Wb, const float* __restrict__ Wa,
    const float* __restrict__ dtb, const float* __restrict__ alog,
    float* __restrict__ beta, float* __restrict__ glog){
  __shared__ float xs[2048];
  __shared__ float rb[256], ra[256];
  const int m = blockIdx.x;
  const float* xr = X + (long)m*2048;
  for (int i = threadIdx.x; i < 512; i += 256)
    ((float4*)xs)[i] = ((const float4*)xr)[i];
  __syncthreads();
  const int n = threadIdx.x & 31, jc = threadIdx.x >> 5;
  const float* wb = Wb + n*2048 + jc*256;
  const float* wa = Wa + n*2048 + jc*256;
  const float* xc = xs + jc*256;
  float sb = 0.f, sa = 0.f;
  for (int i=0;i<256;i++){ float x = xc[i]; sb = fmaf(x, wb[i], sb); sa = fmaf(x, wa[i], sa); }
  rb[threadIdx.x] = sb; ra[threadIdx.x] = sa;
  __syncthreads();
  if (threadIdx.x < 32){
    float b = 0.f, a = 0.f;
    #pragma unroll
    for (int j=0;j<8;j++){ b += rb[threadIdx.x + 32*j]; a += ra[threadIdx.x + 32*j]; }
    beta[(long)m*32 + threadIdx.x] = 1.f/(1.f+expf(-b));
    float ap = a + dtb[threadIdx.x];
    float sp = (ap > 20.f) ? ap : log1pf(expf(ap));
    glog[(long)m*32 + threadIdx.x] = -expf(alog[threadIdx.x]) * sp;   // log decay g
  }
}

// ---------------- causal depthwise conv(K=4) + silu + l2norm(q,k) ----------------
__global__ __launch_bounds__(128) void conv_qkv(const ushort* __restrict__ mixed,
    const float* __restrict__ convw, ushort* __restrict__ qn, ushort* __restrict__ kn,
    ushort* __restrict__ vv){
  const int m = blockIdx.x;
  const int g = blockIdx.y;
  const int s = m & 2047;
  const int c = (g<<7) + threadIdx.x;
  float acc = 0.f;
  #pragma unroll
  for (int j=0;j<4;j++){
    int so = s - 3 + j;
    if (so >= 0) acc += bf2f(mixed[(long)(m-3+j)*8192 + c]) * convw[c*4+j];
  }
  float y = acc / (1.f + expf(-acc));
  if (g < 32){
    float ss = y*y;
    #pragma unroll
    for (int off=32; off; off>>=1) ss += __shfl_xor(ss, off);
    __shared__ float w2[2];
    if ((threadIdx.x&63)==0) w2[threadIdx.x>>6] = ss;
    __syncthreads();
    float r = rsqrtf(w2[0] + w2[1] + 1e-6f);
    if (g < 16) qn[(long)m*2048 + c]          = f2bf(y*r*0.08838834764831845f);
    else        kn[(long)m*2048 + (c-2048)]   = f2bf(y*r);
  } else {
    vv[(long)m*4096 + (c-4096)] = f2bf(y);
  }
}

// ---------------- chunked gated delta-rule (C=32) ----------------
// Grid 64 = (b,h). 4 waves. State S[128dk][128dv] fp32 in MFMA-C-layout registers.
// Per chunk: KK^T,QK^T -> As,M ; B0 = beta*(V - Gam*(K@S0)) ; serial solve (I+Ahat)D=B0 ;
// S = exp(LgC)*S + Kbreve^T@D ; O = exp(Lg_t)*Q@S0 + M@D.
#define MFMA16(a,b,c) __builtin_amdgcn_mfma_f32_16x16x32_bf16(a,b,c,0,0,0)

__global__ __launch_bounds__(256) void chunk_scan(const ushort* __restrict__ qn,
    const ushort* __restrict__ kn, const ushort* __restrict__ vv,
    const float* __restrict__ beta, const float* __restrict__ glog,
    float* __restrict__ o){
  const int bh = blockIdx.x;
  const int b = bh >> 5, h = bh & 31, hq = h >> 1;
  const int tid = threadIdx.x, w = tid >> 6, lane = tid & 63;
  const int quad = lane >> 4, l15 = lane & 15;

  __shared__ ushort Kl[32][136];
  __shared__ ushort Ql[32][136];
  __shared__ ushort KTr[128][40];     // raw K^T [dk][c]
  __shared__ ushort STl[128][136];    // S0^T bf16 [dv][dk]
  __shared__ float  Asl[32][33];      // -Ahat (strict lower)
  __shared__ ushort Msl[32][40];      // M bf16 [t][i]
  __shared__ ushort VTl[128][44];     // V^T bf16 [dv][c]
  __shared__ float  B0T[128][37];     // B0^T fp32 [dv][c]
  __shared__ ushort DTl[128][40];     // D^T bf16 [dv][c]
  __shared__ float  Lgl[32];
  __shared__ float  Btl[32];

  const long tok0 = (long)b*2048;
  const int mtW = w >> 1;             // 32-row matrices: wave's row tile
  const int ntW = (w & 1) * 16;       // 32-col matrices: wave's col base
  const int nt4 = (w & 1) * 4;        // 128-col outputs: wave's col-tile base
  const int sc = tid >> 3;            // staging: chunk row
  const int ss = (tid & 7) * 16;      // staging: col base (16 ushorts)

  f32x4 S[2][8];                      // tiles (mt=2w+ti, nt)
  #pragma unroll
  for (int i=0;i<2;i++)
    #pragma unroll
    for (int j=0;j<8;j++) S[i][j] = (f32x4){0.f,0.f,0.f,0.f};

  for (int ch = 0; ch < 64; ch++){
    const long tch = tok0 + ch*32;
    // ---- phase 1: dump S0^T, stage K/Q/V (+transposes), Lg prefix ----
    #pragma unroll
    for (int ti=0; ti<2; ti++){
      const int m0 = (2*w+ti)*16 + quad*4;
      #pragma unroll
      for (int nt=0; nt<8; nt++){
        const int n = nt*16 + l15;
        ushort4 pk;
        pk.x = f2bf(S[ti][nt][0]); pk.y = f2bf(S[ti][nt][1]);
        pk.z = f2bf(S[ti][nt][2]); pk.w = f2bf(S[ti][nt][3]);
        *(ushort4*)&STl[n][m0] = pk;
      }
    }
    if (tid < 64){
      const int c = lane & 31;
      float gv = glog[(tch + c)*32 + h];
      float bv = beta[(tch + c)*32 + h];
      #pragma unroll
      for (int off=1; off<32; off<<=1){
        float t = __shfl_up(gv, off);
        if ((lane & 31) >= off) gv += t;
      }
      if (lane < 32){ Lgl[c] = gv; Btl[c] = bv; }
    }
    {
      __attribute__((aligned(16))) ushort kv[16], qv[16], vv16[16];
      const ushort* kp = kn + (tch+sc)*2048 + hq*128 + ss;
      const ushort* qp = qn + (tch+sc)*2048 + hq*128 + ss;
      const ushort* vp = vv + (tch+sc)*4096 + h*128 + ss;
      *(u32x4*)&kv[0] = *(const u32x4*)kp;  *(u32x4*)&kv[8] = *(const u32x4*)(kp+8);
      *(u32x4*)&qv[0] = *(const u32x4*)qp;  *(u32x4*)&qv[8] = *(const u32x4*)(qp+8);
      *(u32x4*)&vv16[0] = *(const u32x4*)vp; *(u32x4*)&vv16[8] = *(const u32x4*)(vp+8);
      *(u32x4*)&Kl[sc][ss] = *(u32x4*)&kv[0]; *(u32x4*)&Kl[sc][ss+8] = *(u32x4*)&kv[8];
      *(u32x4*)&Ql[sc][ss] = *(u32x4*)&qv[0]; *(u32x4*)&Ql[sc][ss+8] = *(u32x4*)&qv[8];
      #pragma unroll
      for (int e=0;e<16;e++){
        KTr[ss+e][sc] = kv[e];
        VTl[ss+e][sc] = vv16[e];
      }
    }
    __syncthreads();

    // ---- phase 2: MFMAs + As/Ms/B0 ----
    const float LgC = Lgl[31];
    const int rA = mtW*16 + l15;
    s16x8 ka[4], qa[4], kb[4];
    #pragma unroll
    for (int ks=0; ks<4; ks++){
      ka[ks] = *(const s16x8*)&Kl[rA][ks*32 + quad*8];
      qa[ks] = *(const s16x8*)&Ql[rA][ks*32 + quad*8];
      kb[ks] = *(const s16x8*)&Kl[ntW + l15][ks*32 + quad*8];
    }
    f32x4 accK = (f32x4){0.f,0.f,0.f,0.f}, accQ = (f32x4){0.f,0.f,0.f,0.f};
    #pragma unroll
    for (int ks=0; ks<4; ks++){
      accK = MFMA16(ka[ks], kb[ks], accK);
      accQ = MFMA16(qa[ks], kb[ks], accQ);
    }
    f32x4 KS4[4], O4[4];
    #pragma unroll
    for (int tt=0; tt<4; tt++){
      const int n = (nt4+tt)*16 + l15;
      f32x4 aK = (f32x4){0.f,0.f,0.f,0.f}, aQ = (f32x4){0.f,0.f,0.f,0.f};
      #pragma unroll
      for (int ks=0; ks<4; ks++){
        s16x8 sb = *(const s16x8*)&STl[n][ks*32 + quad*8];
        aK = MFMA16(ka[ks], sb, aK);
        aQ = MFMA16(qa[ks], sb, aQ);
      }
      KS4[tt] = aK; O4[tt] = aQ;
    }
    const int c0 = mtW*16 + quad*4;
    float Lg4[4], bt4[4], eLg4[4];
    #pragma unroll
    for (int i=0;i<4;i++){ Lg4[i] = Lgl[c0+i]; bt4[i] = Btl[c0+i]; eLg4[i] = expf(Lg4[i]); }
    {
      const int j = ntW + l15;
      const float Lgj = Lgl[j];
      #pragma unroll
      for (int i=0;i<4;i++){
        const int r = c0 + i;
        Asl[r][j] = (r > j) ? -bt4[i]*expf(Lg4[i]-Lgj)*accK[i] : 0.f;
        Msl[r][j] = (r >= j) ? f2bf(expf(Lg4[i]-Lgj)*accQ[i]) : (ushort)0;
      }
    }
    #pragma unroll
    for (int tt=0; tt<4; tt++){
      const int dv = (nt4+tt)*16 + l15;
      ushort4 v4 = *(const ushort4*)&VTl[dv][c0];
      float vf[4] = {bf2f(v4.x), bf2f(v4.y), bf2f(v4.z), bf2f(v4.w)};
      #pragma unroll
      for (int i=0;i<4;i++){
        O4[tt][i] *= eLg4[i];
        B0T[dv][c0+i] = bt4[i]*(vf[i] - eLg4[i]*KS4[tt][i]);
      }
    }
    __syncthreads();

    // ---- phase 3: serial forward-substitution solve (128 lanes = dv cols) ----
    if (tid < 128){
      const int dv = tid;
      float d[32];
      #pragma unroll
      for (int c=0; c<32; c++){
        float acc = B0T[dv][c];
        #pragma unroll
        for (int j=0; j<c; j++) acc = fmaf(Asl[c][j], d[j], acc);
        d[c] = acc;
        DTl[dv][c] = f2bf(acc);
      }
    }
    __syncthreads();

    // ---- phase 4: state update + output ----
    const float eC = expf(LgC);
    #pragma unroll
    for (int ti=0; ti<2; ti++)
      #pragma unroll
      for (int nt=0; nt<8; nt++)
        #pragma unroll
        for (int i=0;i<4;i++) S[ti][nt][i] *= eC;

    float ks8[8];
    #pragma unroll
    for (int j=0;j<8;j++) ks8[j] = expf(LgC - Lgl[quad*8 + j]);
    s16x8 kta[2];
    #pragma unroll
    for (int ti=0; ti<2; ti++){
      s16x8 raw = *(const s16x8*)&KTr[(2*w+ti)*16 + l15][quad*8];
      s16x8 sca;
      #pragma unroll
      for (int j=0;j<8;j++) sca[j] = (short)f2bf(bf2f((ushort)raw[j]) * ks8[j]);
      kta[ti] = sca;
    }
    s16x8 db[8];
    #pragma unroll
    for (int nt=0; nt<8; nt++)
      db[nt] = *(const s16x8*)&DTl[nt*16 + l15][quad*8];
    #pragma unroll
    for (int ti=0; ti<2; ti++)
      #pragma unroll
      for (int nt=0; nt<8; nt++)
        S[ti][nt] = MFMA16(kta[ti], db[nt], S[ti][nt]);

    s16x8 ma = *(const s16x8*)&Msl[rA][quad*8];
    #pragma unroll
    for (int tt=0; tt<4; tt++)
      O4[tt] = MFMA16(ma, db[nt4+tt], O4[tt]);

    #pragma unroll
    for (int tt=0; tt<4; tt++){
      const int dv = (nt4+tt)*16 + l15;
      #pragma unroll
      for (int i=0;i<4;i++){
        const int t = c0 + i;
        o[(tch + t)*4096 + h*128 + dv] = O4[tt][i];
      }
    }
    __syncthreads();
  }
}

// ---------------- RMSNorm(gated) + silu(z) gate, bf16 out ----------------
__global__ __launch_bounds__(128) void norm_gate(const float* __restrict__ o,
    const ushort* __restrict__ z, const float* __restrict__ normw,
    ushort* __restrict__ og){
  const long mh = blockIdx.x;
  const int d = threadIdx.x;
  float x = o[mh*128 + d];
  float ss = x*x;
  #pragma unroll
  for (int off=32; off; off>>=1) ss += __shfl_xor(ss, off);
  __shared__ float w2[2];
  if ((d&63)==0) w2[d>>6] = ss;
  __syncthreads();
  float r = rsqrtf((w2[0]+w2[1])*(1.f/128.f) + 1e-6f);
  float zz = bf2f(z[mh*128 + d]);
  float sil = zz / (1.f + expf(-zz));
  og[mh*128 + d] = f2bf(x*r*normw[d]*sil);
}

extern "C" void kernel_launch(void* const* d_in, const int* in_sizes, int n_in,
                              void* d_out, int out_size, void* d_ws, size_t ws_size,
                              hipStream_t stream){
  const float* hs    = (const float*)d_in[0];
  const float* Wqkv  = (const float*)d_in[1];
  const float* Wz    = (const float*)d_in[2];
  const float* Wb    = (const float*)d_in[3];
  const float* Wa    = (const float*)d_in[4];
  const float* convw = (const float*)d_in[5];
  const float* normw = (const float*)d_in[6];
  const float* Wout  = (const float*)d_in[7];
  const float* dtb   = (const float*)d_in[8];
  const float* alog  = (const float*)d_in[9];

  char* ws = (char*)d_ws;
  ushort* hsb   = (ushort*)(ws);                 // [0,16M)    hs bf16  -> later kn
  ushort* wqb   = (ushort*)(ws + (16l<<20));     // [16,48M)   Wqkv bf16 -> later v -> og
  ushort* wzb   = (ushort*)(ws + (48l<<20));     // [48,64M)   Wz bf16  -> later qn
  ushort* wob   = (ushort*)(ws + (64l<<20));     // [64,80M)   Wout bf16
  ushort* mixed = (ushort*)(ws + (80l<<20));     // [80,144M)  mixed bf16 -> later o_raw f32
  ushort* zb    = (ushort*)(ws + (144l<<20));    // [144,176M) z bf16
  float*  beta  = (float*)(ws + (176l<<20));
  float*  glog  = (float*)(ws + (177l<<20));
  ushort* kn = hsb;  ushort* qn = wzb;  ushort* vvp = wqb;  ushort* og = wqb;
  float*  o_raw = (float*)mixed;

  cvt_bf16<<<8192,  256, 0, stream>>>(hs,   hsb);
  cvt_bf16<<<16384, 256, 0, stream>>>(Wqkv, wqb);
  cvt_bf16<<<8192,  256, 0, stream>>>(Wz,   wzb);
  cvt_bf16<<<8192,  256, 0, stream>>>(Wout, wob);

  gemm_bt<1><<<32*64, 256, 0, stream>>>(hsb, wqb, (void*)mixed, 4096, 8192, 2048);
  gemm_bt<1><<<32*32, 256, 0, stream>>>(hsb, wzb, (void*)zb,    4096, 4096, 2048);
  proj_ba<<<4096, 256, 0, stream>>>(hs, Wb, Wa, dtb, alog, beta, glog);

  conv_qkv<<<dim3(4096,64), 128, 0, stream>>>(mixed, convw, qn, kn, vvp);
  chunk_scan<<<64, 256, 0, stream>>>(qn, kn, vvp, beta, glog, o_raw);
  norm_gate<<<131072, 128, 0, stream>>>(o_raw, zb, normw, og);

  gemm_bt<0><<<32*16, 256, 0, stream>>>(og, wob, d_out, 4096, 2048, 4096);
}

// Round 4
// 1119.162 us; speedup vs baseline: 2.0999x; 2.0999x over previous
//
#include <hip/hip_runtime.h>
#include <hip/hip_bf16.h>
#include <math.h>

#define DEVI __device__ __forceinline__

typedef __attribute__((ext_vector_type(4))) float f32x4;
typedef __attribute__((ext_vector_type(8))) short s16x8;
typedef __attribute__((ext_vector_type(4))) unsigned int u32x4;

DEVI float bf2f(ushort u){ union{unsigned int i; float f;} x; x.i = ((unsigned int)u)<<16; return x.f; }
DEVI ushort f2bf(float f){ union{float f; unsigned int i;} x; x.f = f;
  unsigned int r = x.i + 0x7fffu + ((x.i>>16)&1u); return (ushort)(r>>16); }

#define MFMA16(a,b,c) __builtin_amdgcn_mfma_f32_16x16x32_bf16(a,b,c,0,0,0)

// ---------------- fp32 -> bf16 convert, 4 elems/thread ----------------
__global__ __launch_bounds__(256) void cvt_bf16(const float* __restrict__ in, ushort* __restrict__ out){
  int i = blockIdx.x*256 + threadIdx.x;
  float4 v = ((const float4*)in)[i];
  ushort4 o; o.x = f2bf(v.x); o.y = f2bf(v.y); o.z = f2bf(v.z); o.w = f2bf(v.w);
  ((ushort4*)out)[i] = o;
}

// ---------------- bf16 MFMA GEMM: C[M,N] = A[M,K] * B[N,K]^T ----------------
DEVI void gl_lds16(const ushort* g, ushort* l){
  __builtin_amdgcn_global_load_lds((const __attribute__((address_space(1))) void*)g,
                                   (__attribute__((address_space(3))) void*)l, 16, 0, 0);
}

template<int BF16_OUT>
__global__ __launch_bounds__(256, 2) void gemm_bt(const ushort* __restrict__ A,
                                                  const ushort* __restrict__ B,
                                                  void* __restrict__ Cv,
                                                  int M, int N, int K){
  __shared__ ushort As[128*32];
  __shared__ ushort Bs[128*32];
  const int nb = N >> 7;
  const int tile_m = (blockIdx.x / nb) << 7;
  const int tile_n = (blockIdx.x % nb) << 7;
  const int tid  = threadIdx.x;
  const int w    = tid >> 6;
  const int lane = tid & 63;

  const int ca = w*2;
  const long rowA = tile_m + ca*16 + (lane>>2);
  const long rowB = tile_n + ca*16 + (lane>>2);
  const int  colE = (lane&3)*8;
  const ushort* pA0 = A + rowA*(long)K + colE;
  const ushort* pA1 = pA0 + 16l*K;
  const ushort* pB0 = B + rowB*(long)K + colE;
  const ushort* pB1 = pB0 + 16l*K;
  ushort* lA0 = As + ca*512;
  ushort* lA1 = As + ca*512 + 512;
  ushort* lB0 = Bs + ca*512;
  ushort* lB1 = Bs + ca*512 + 512;

  const int wr = (w>>1)<<6;
  const int wc = (w&1)<<6;
  const int fr = lane & 15;
  const int fk = (lane>>4)<<3;

  f32x4 acc[4][4];
  #pragma unroll
  for (int i=0;i<4;i++)
    #pragma unroll
    for (int j=0;j<4;j++) acc[i][j] = (f32x4){0.f,0.f,0.f,0.f};

  for (int k0 = 0; k0 < K; k0 += 32){
    __syncthreads();
    gl_lds16(pA0, lA0);
    gl_lds16(pA1, lA1);
    gl_lds16(pB0, lB0);
    gl_lds16(pB1, lB1);
    __syncthreads();
    s16x8 af[4], bfr[4];
    #pragma unroll
    for (int t=0;t<4;t++){
      af[t]  = *(const s16x8*)(As + (wr + t*16 + fr)*32 + fk);
      bfr[t] = *(const s16x8*)(Bs + (wc + t*16 + fr)*32 + fk);
    }
    #pragma unroll
    for (int mt=0;mt<4;mt++)
      #pragma unroll
      for (int nt=0;nt<4;nt++)
        acc[mt][nt] = MFMA16(af[mt], bfr[nt], acc[mt][nt]);
    pA0 += 32; pA1 += 32; pB0 += 32; pB1 += 32;
  }

  const int crow = tile_m + wr + ((lane>>4)<<2);
  const int ccol = tile_n + wc + (lane&15);
  if (BF16_OUT){
    ushort* C = (ushort*)Cv;
    #pragma unroll
    for (int mt=0;mt<4;mt++)
      #pragma unroll
      for (int r=0;r<4;r++){
        long row = crow + mt*16 + r;
        #pragma unroll
        for (int nt=0;nt<4;nt++)
          C[row*(long)N + ccol + nt*16] = f2bf(acc[mt][nt][r]);
      }
  } else {
    float* C = (float*)Cv;
    #pragma unroll
    for (int mt=0;mt<4;mt++)
      #pragma unroll
      for (int r=0;r<4;r++){
        long row = crow + mt*16 + r;
        #pragma unroll
        for (int nt=0;nt<4;nt++)
          C[row*(long)N + ccol + nt*16] = acc[mt][nt][r];
      }
  }
}

// ---------------- beta / log-decay projection (fp32 precise) ----------------
__global__ __launch_bounds__(256) void proj_ba(const float* __restrict__ X,
    const float* __restrict__ Wb, const float* __restrict__ Wa,
    const float* __restrict__ dtb, const float* __restrict__ alog,
    float* __restrict__ beta, float* __restrict__ glog){
  __shared__ float xs[2048];
  __shared__ float rb[256], ra[256];
  const int m = blockIdx.x;
  const float* xr = X + (long)m*2048;
  for (int i = threadIdx.x; i < 512; i += 256)
    ((float4*)xs)[i] = ((const float4*)xr)[i];
  __syncthreads();
  const int n = threadIdx.x & 31, jc = threadIdx.x >> 5;
  const float* wb = Wb + n*2048 + jc*256;
  const float* wa = Wa + n*2048 + jc*256;
  const float* xc = xs + jc*256;
  float sb = 0.f, sa = 0.f;
  for (int i=0;i<256;i++){ float x = xc[i]; sb = fmaf(x, wb[i], sb); sa = fmaf(x, wa[i], sa); }
  rb[threadIdx.x] = sb; ra[threadIdx.x] = sa;
  __syncthreads();
  if (threadIdx.x < 32){
    float b = 0.f, a = 0.f;
    #pragma unroll
    for (int j=0;j<8;j++){ b += rb[threadIdx.x + 32*j]; a += ra[threadIdx.x + 32*j]; }
    beta[(long)m*32 + threadIdx.x] = 1.f/(1.f+expf(-b));
    float ap = a + dtb[threadIdx.x];
    float sp = (ap > 20.f) ? ap : log1pf(expf(ap));
    glog[(long)m*32 + threadIdx.x] = -expf(alog[threadIdx.x]) * sp;   // log decay g
  }
}

// ---------------- causal depthwise conv(K=4) + silu + l2norm(q,k) ----------------
__global__ __launch_bounds__(128) void conv_qkv(const ushort* __restrict__ mixed,
    const float* __restrict__ convw, ushort* __restrict__ qn, ushort* __restrict__ kn,
    ushort* __restrict__ vv){
  const int m = blockIdx.x;
  const int g = blockIdx.y;
  const int s = m & 2047;
  const int c = (g<<7) + threadIdx.x;
  float acc = 0.f;
  #pragma unroll
  for (int j=0;j<4;j++){
    int so = s - 3 + j;
    if (so >= 0) acc += bf2f(mixed[(long)(m-3+j)*8192 + c]) * convw[c*4+j];
  }
  float y = acc / (1.f + expf(-acc));
  if (g < 32){
    float ss = y*y;
    #pragma unroll
    for (int off=32; off; off>>=1) ss += __shfl_xor(ss, off);
    __shared__ float w2[2];
    if ((threadIdx.x&63)==0) w2[threadIdx.x>>6] = ss;
    __syncthreads();
    float r = rsqrtf(w2[0] + w2[1] + 1e-6f);
    if (g < 16) qn[(long)m*2048 + c]          = f2bf(y*r*0.08838834764831845f);
    else        kn[(long)m*2048 + (c-2048)]   = f2bf(y*r);
  } else {
    vv[(long)m*4096 + (c-4096)] = f2bf(y);
  }
}

// ---------------- pass 1: per-chunk T=(I+Ahat)^-1, M, cumLg (parallel, 4096 blocks) --------
// bid = bh*64 + ch. Ahat[r][j] = beta_r*exp(Lg_r-Lg_j)*(k_r.k_j) (r>j);
// M[t][j] = exp(Lg_t-Lg_j)*(q_t.k_j) (t>=j). T solved by forward substitution per column.
__global__ __launch_bounds__(256) void chunk_prep(
    const ushort* __restrict__ qn, const ushort* __restrict__ kn,
    const float* __restrict__ beta, const float* __restrict__ glog,
    ushort* __restrict__ Tg, ushort* __restrict__ Mg, float* __restrict__ cumLgG){
  const int bid = blockIdx.x;
  const int bh = bid >> 6, ch = bid & 63;
  const int b = bh>>5, h = bh&31, hq = h>>1;
  const long tch = (long)b*2048 + ch*32;
  const int tid = threadIdx.x, w = tid>>6, lane = tid&63;
  const int quad = lane>>4, l15 = lane&15;

  __shared__ __attribute__((aligned(16))) ushort Kl[32][136];
  __shared__ __attribute__((aligned(16))) ushort Ql[32][136];
  __shared__ float Asl[32][33];
  __shared__ float Lgl[32], Btl[32];

  const int sc = tid>>3, ss = (tid&7)*16;
  {
    const ushort* kp = kn + (tch+sc)*2048 + hq*128 + ss;
    const ushort* qp = qn + (tch+sc)*2048 + hq*128 + ss;
    *(u32x4*)&Kl[sc][ss] = *(const u32x4*)kp; *(u32x4*)&Kl[sc][ss+8] = *(const u32x4*)(kp+8);
    *(u32x4*)&Ql[sc][ss] = *(const u32x4*)qp; *(u32x4*)&Ql[sc][ss+8] = *(const u32x4*)(qp+8);
  }
  if (tid < 64){
    const int c = lane & 31;
    float gv = glog[(tch + c)*32 + h];
    float bv = beta[(tch + c)*32 + h];
    #pragma unroll
    for (int off=1; off<32; off<<=1){
      float t = __shfl_up(gv, off);
      if ((lane & 31) >= off) gv += t;
    }
    if (lane < 32){ Lgl[c] = gv; Btl[c] = bv; cumLgG[(long)bid*32 + c] = gv; }
  }
  __syncthreads();

  const int mt = w>>1, nt = w&1;
  s16x8 ka[4], qa[4], kb[4];
  #pragma unroll
  for (int ks=0; ks<4; ks++){
    ka[ks] = *(const s16x8*)&Kl[mt*16+l15][ks*32 + quad*8];
    qa[ks] = *(const s16x8*)&Ql[mt*16+l15][ks*32 + quad*8];
    kb[ks] = *(const s16x8*)&Kl[nt*16+l15][ks*32 + quad*8];
  }
  f32x4 accK = (f32x4){0.f,0.f,0.f,0.f}, accQ = (f32x4){0.f,0.f,0.f,0.f};
  #pragma unroll
  for (int ks=0; ks<4; ks++){
    accK = MFMA16(ka[ks], kb[ks], accK);
    accQ = MFMA16(qa[ks], kb[ks], accQ);
  }
  const int j = nt*16 + l15;
  const float Lgj = Lgl[j];
  #pragma unroll
  for (int i=0;i<4;i++){
    const int r = mt*16 + quad*4 + i;
    const float e = expf(Lgl[r]-Lgj);
    Asl[r][j] = (r>j) ? -Btl[r]*e*accK[i] : 0.f;   // = -Ahat
    Mg[(long)bid*1024 + r*32 + j] = (r>=j) ? f2bf(e*accQ[i]) : (ushort)0;
  }
  __syncthreads();

  if (tid < 32){
    const int jc = tid;
    float tc[32];
    #pragma unroll
    for (int c=0;c<32;c++){
      float acc = (c==jc) ? 1.f : 0.f;
      #pragma unroll
      for (int i2=0;i2<c;i2++) acc = fmaf(Asl[c][i2], tc[i2], acc);
      tc[c] = acc;
      Tg[(long)bid*1024 + c*32 + jc] = f2bf(acc);
    }
  }
}

// ---------------- pass 2: sequential inter-chunk recurrence, MFMA only ----------------
// grid 256 = sl(0..3)*64 + bh; block owns dv slice of 32. S[128dk][32dv] fp32 regs
// (tiles mt=2w+ti, nt=0..1). Per chunk: X=K@S0, Y=Q@S0, B0=beta(V-Gam*X),
// D^T=B0^T@T^T (1 MFMA), O=Gam*Y+M@D, S=eC*S+Kbreve^T@D.
__global__ __launch_bounds__(256) void chunk_scan2(
    const ushort* __restrict__ qn, const ushort* __restrict__ kn,
    const ushort* __restrict__ vv, const float* __restrict__ beta,
    const float* __restrict__ cumLg, const ushort* __restrict__ Tg,
    const ushort* __restrict__ Mg, float* __restrict__ o){
  const int bh = blockIdx.x & 63, sl = blockIdx.x >> 6;
  const int b = bh>>5, h = bh&31, hq = h>>1;
  const int dv0 = sl*32;
  const int tid = threadIdx.x, w = tid>>6, lane = tid&63;
  const int quad = lane>>4, l15 = lane&15;
  const int mtx = w>>1, ntx = w&1;         // tile coords for X/Y/O/D
  const int sc = tid>>3, ss = (tid&7)*16;  // K^T staging
  const int c0 = mtx*16 + quad*4;

  __shared__ __attribute__((aligned(16))) ushort STl[32][136];
  __shared__ __attribute__((aligned(16))) ushort KTl[128][40];
  __shared__ __attribute__((aligned(16))) ushort B0T[32][40];
  __shared__ __attribute__((aligned(16))) ushort DT[32][40];
  __shared__ float Lgc[32], Btf[32], eLgl[32], eDf[32];

  f32x4 S[2][2];
  #pragma unroll
  for (int i=0;i<2;i++)
    #pragma unroll
    for (int j2=0;j2<2;j2++) S[i][j2] = (f32x4){0.f,0.f,0.f,0.f};

  for (int ch=0; ch<64; ch++){
    const long tch = (long)b*2048 + ch*32;
    const long pb = (long)bh*64 + ch;
    // ---- phase A: scalars, dump S^T, stage K^T ----
    if (tid < 32){
      float lg = cumLg[pb*32 + tid];
      float lgC = __shfl(lg, 31);
      Lgc[tid] = lg;
      Btf[tid] = beta[(tch + tid)*32 + h];
      eLgl[tid] = expf(lg);
      eDf[tid]  = expf(lgC - lg);
    }
    #pragma unroll
    for (int ti=0; ti<2; ti++){
      const int m0 = (2*w+ti)*16 + quad*4;
      #pragma unroll
      for (int nt=0; nt<2; nt++){
        const int n = nt*16 + l15;
        ushort4 pk;
        pk.x = f2bf(S[ti][nt][0]); pk.y = f2bf(S[ti][nt][1]);
        pk.z = f2bf(S[ti][nt][2]); pk.w = f2bf(S[ti][nt][3]);
        *(ushort4*)&STl[n][m0] = pk;
      }
    }
    {
      __attribute__((aligned(16))) ushort kv[16];
      const ushort* kp = kn + (tch+sc)*2048 + hq*128 + ss;
      *(u32x4*)&kv[0] = *(const u32x4*)kp;
      *(u32x4*)&kv[8] = *(const u32x4*)(kp+8);
      #pragma unroll
      for (int e=0;e<16;e++) KTl[ss+e][sc] = kv[e];
    }
    __syncthreads();

    // ---- phase B: X=K@S0, Y=Q@S0, B0, dump B0^T ----
    f32x4 X = (f32x4){0.f,0.f,0.f,0.f}, Y = (f32x4){0.f,0.f,0.f,0.f};
    {
      const ushort* kA = kn + (tch + mtx*16 + l15)*2048 + hq*128 + quad*8;
      const ushort* qA = qn + (tch + mtx*16 + l15)*2048 + hq*128 + quad*8;
      #pragma unroll
      for (int ks=0; ks<4; ks++){
        s16x8 af = *(const s16x8*)(kA + ks*32);
        s16x8 qf = *(const s16x8*)(qA + ks*32);
        s16x8 sb = *(const s16x8*)&STl[ntx*16 + l15][ks*32 + quad*8];
        X = MFMA16(af, sb, X);
        Y = MFMA16(qf, sb, Y);
      }
    }
    #pragma unroll
    for (int i=0;i<4;i++){
      const int c = c0+i;
      float vval = bf2f(vv[(tch+c)*4096 + h*128 + dv0 + ntx*16 + l15]);
      float b0 = Btf[c]*(vval - eLgl[c]*X[i]);
      B0T[ntx*16 + l15][c] = f2bf(b0);       // [dv][c]
      Y[i] *= eLgl[c];
    }
    __syncthreads();

    // ---- phase C: D^T = B0^T @ T^T (one MFMA per wave) ----
    {
      s16x8 a  = *(const s16x8*)&B0T[mtx*16 + l15][quad*8];
      s16x8 bT = *(const s16x8*)(Tg + pb*1024 + (ntx*16 + l15)*32 + quad*8);
      f32x4 Dt = MFMA16(a, bT, ((f32x4){0.f,0.f,0.f,0.f}));
      #pragma unroll
      for (int i=0;i<4;i++)
        DT[mtx*16 + quad*4 + i][ntx*16 + l15] = f2bf(Dt[i]);   // [dv][c]
    }
    __syncthreads();

    // ---- phase D: O = Gam*Y + M@D ; S = eC*S + Kbreve^T@D ----
    {
      s16x8 ma = *(const s16x8*)(Mg + pb*1024 + (mtx*16+l15)*32 + quad*8);
      s16x8 db = *(const s16x8*)&DT[ntx*16 + l15][quad*8];
      f32x4 O = MFMA16(ma, db, Y);
      #pragma unroll
      for (int i=0;i<4;i++)
        o[(tch + c0 + i)*4096 + h*128 + dv0 + ntx*16 + l15] = O[i];
    }
    {
      const float eC = eLgl[31];
      float ed[8];
      #pragma unroll
      for (int j2=0;j2<8;j2++) ed[j2] = eDf[quad*8+j2];
      s16x8 kta[2], dfr[2];
      #pragma unroll
      for (int ti=0; ti<2; ti++){
        s16x8 raw = *(const s16x8*)&KTl[(2*w+ti)*16 + l15][quad*8];
        s16x8 sca;
        #pragma unroll
        for (int j2=0;j2<8;j2++) sca[j2] = (short)f2bf(bf2f((ushort)raw[j2])*ed[j2]);
        kta[ti] = sca;
        dfr[ti] = *(const s16x8*)&DT[ti*16 + l15][quad*8];
      }
      #pragma unroll
      for (int ti=0; ti<2; ti++)
        #pragma unroll
        for (int nt=0; nt<2; nt++){
          f32x4 t;
          #pragma unroll
          for (int i=0;i<4;i++) t[i] = S[ti][nt][i]*eC;
          S[ti][nt] = MFMA16(kta[ti], dfr[nt], t);
        }
    }
    __syncthreads();
  }
}

// ---------------- RMSNorm(gated) + silu(z) gate, bf16 out ----------------
__global__ __launch_bounds__(128) void norm_gate(const float* __restrict__ o,
    const ushort* __restrict__ z, const float* __restrict__ normw,
    ushort* __restrict__ og){
  const long mh = blockIdx.x;
  const int d = threadIdx.x;
  float x = o[mh*128 + d];
  float ss = x*x;
  #pragma unroll
  for (int off=32; off; off>>=1) ss += __shfl_xor(ss, off);
  __shared__ float w2[2];
  if ((d&63)==0) w2[d>>6] = ss;
  __syncthreads();
  float r = rsqrtf((w2[0]+w2[1])*(1.f/128.f) + 1e-6f);
  float zz = bf2f(z[mh*128 + d]);
  float sil = zz / (1.f + expf(-zz));
  og[mh*128 + d] = f2bf(x*r*normw[d]*sil);
}

extern "C" void kernel_launch(void* const* d_in, const int* in_sizes, int n_in,
                              void* d_out, int out_size, void* d_ws, size_t ws_size,
                              hipStream_t stream){
  const float* hs    = (const float*)d_in[0];
  const float* Wqkv  = (const float*)d_in[1];
  const float* Wz    = (const float*)d_in[2];
  const float* Wb    = (const float*)d_in[3];
  const float* Wa    = (const float*)d_in[4];
  const float* convw = (const float*)d_in[5];
  const float* normw = (const float*)d_in[6];
  const float* Wout  = (const float*)d_in[7];
  const float* dtb   = (const float*)d_in[8];
  const float* alog  = (const float*)d_in[9];

  char* ws = (char*)d_ws;
  ushort* hsb   = (ushort*)(ws);                 // [0,16M)    hs bf16  -> later kn
  ushort* wqb   = (ushort*)(ws + (16l<<20));     // [16,48M)   Wqkv bf16 -> later v -> og
  ushort* wzb   = (ushort*)(ws + (48l<<20));     // [48,64M)   Wz bf16  -> later qn
  ushort* wob   = (ushort*)(ws + (64l<<20));     // [64,80M)   Wout bf16
  ushort* mixed = (ushort*)(ws + (80l<<20));     // [80,144M)  mixed bf16 -> later o_raw f32
  ushort* zb    = (ushort*)(ws + (144l<<20));    // [144,176M) z bf16
  float*  beta  = (float*)(ws + (176l<<20));     // 512K
  float*  cumLg = (float*)(ws + (176l<<20) + (512l<<10)); // 512K
  float*  glog  = (float*)(ws + (177l<<20));     // 512K
  ushort* Tg    = (ushort*)(ws + (178l<<20));    // [178,186M) T bf16
  ushort* Mg    = (ushort*)(ws + (186l<<20));    // [186,194M) M bf16
  ushort* kn = hsb;  ushort* qn = wzb;  ushort* vvp = wqb;  ushort* og = wqb;
  float*  o_raw = (float*)mixed;

  cvt_bf16<<<8192,  256, 0, stream>>>(hs,   hsb);
  cvt_bf16<<<16384, 256, 0, stream>>>(Wqkv, wqb);
  cvt_bf16<<<8192,  256, 0, stream>>>(Wz,   wzb);
  cvt_bf16<<<8192,  256, 0, stream>>>(Wout, wob);

  gemm_bt<1><<<32*64, 256, 0, stream>>>(hsb, wqb, (void*)mixed, 4096, 8192, 2048);
  gemm_bt<1><<<32*32, 256, 0, stream>>>(hsb, wzb, (void*)zb,    4096, 4096, 2048);
  proj_ba<<<4096, 256, 0, stream>>>(hs, Wb, Wa, dtb, alog, beta, glog);

  conv_qkv<<<dim3(4096,64), 128, 0, stream>>>(mixed, convw, qn, kn, vvp);
  chunk_prep<<<4096, 256, 0, stream>>>(qn, kn, beta, glog, Tg, Mg, cumLg);
  chunk_scan2<<<256, 256, 0, stream>>>(qn, kn, vvp, beta, cumLg, Tg, Mg, o_raw);
  norm_gate<<<131072, 128, 0, stream>>>(o_raw, zb, normw, og);

  gemm_bt<0><<<32*16, 256, 0, stream>>>(og, wob, d_out, 4096, 2048, 4096);
}

// Round 5
// 943.804 us; speedup vs baseline: 2.4901x; 1.1858x over previous
//
#include <hip/hip_runtime.h>
#include <hip/hip_bf16.h>
#include <math.h>

#define DEVI __device__ __forceinline__

typedef __attribute__((ext_vector_type(4))) float f32x4;
typedef __attribute__((ext_vector_type(8))) short s16x8;
typedef __attribute__((ext_vector_type(4))) unsigned int u32x4;

DEVI float bf2f(ushort u){ union{unsigned int i; float f;} x; x.i = ((unsigned int)u)<<16; return x.f; }
DEVI ushort f2bf(float f){ union{float f; unsigned int i;} x; x.f = f;
  unsigned int r = x.i + 0x7fffu + ((x.i>>16)&1u); return (ushort)(r>>16); }

#define MFMA16(a,b,c) __builtin_amdgcn_mfma_f32_16x16x32_bf16(a,b,c,0,0,0)

// ---------------- fp32 -> bf16 convert, 4 elems/thread ----------------
__global__ __launch_bounds__(256) void cvt_bf16(const float* __restrict__ in, ushort* __restrict__ out){
  int i = blockIdx.x*256 + threadIdx.x;
  float4 v = ((const float4*)in)[i];
  ushort4 o; o.x = f2bf(v.x); o.y = f2bf(v.y); o.z = f2bf(v.z); o.w = f2bf(v.w);
  ((ushort4*)out)[i] = o;
}

// ---------------- bf16 MFMA GEMM: C[M,N] = A[M,K] * B[N,K]^T ----------------
DEVI void gl_lds16(const ushort* g, ushort* l){
  __builtin_amdgcn_global_load_lds((const __attribute__((address_space(1))) void*)g,
                                   (__attribute__((address_space(3))) void*)l, 16, 0, 0);
}

template<int BF16_OUT>
__global__ __launch_bounds__(256, 2) void gemm_bt(const ushort* __restrict__ A,
                                                  const ushort* __restrict__ B,
                                                  void* __restrict__ Cv,
                                                  int M, int N, int K){
  __shared__ ushort As[128*32];
  __shared__ ushort Bs[128*32];
  const int nb = N >> 7;
  const int tile_m = (blockIdx.x / nb) << 7;
  const int tile_n = (blockIdx.x % nb) << 7;
  const int tid  = threadIdx.x;
  const int w    = tid >> 6;
  const int lane = tid & 63;

  const int ca = w*2;
  const long rowA = tile_m + ca*16 + (lane>>2);
  const long rowB = tile_n + ca*16 + (lane>>2);
  const int  colE = (lane&3)*8;
  const ushort* pA0 = A + rowA*(long)K + colE;
  const ushort* pA1 = pA0 + 16l*K;
  const ushort* pB0 = B + rowB*(long)K + colE;
  const ushort* pB1 = pB0 + 16l*K;
  ushort* lA0 = As + ca*512;
  ushort* lA1 = As + ca*512 + 512;
  ushort* lB0 = Bs + ca*512;
  ushort* lB1 = Bs + ca*512 + 512;

  const int wr = (w>>1)<<6;
  const int wc = (w&1)<<6;
  const int fr = lane & 15;
  const int fk = (lane>>4)<<3;

  f32x4 acc[4][4];
  #pragma unroll
  for (int i=0;i<4;i++)
    #pragma unroll
    for (int j=0;j<4;j++) acc[i][j] = (f32x4){0.f,0.f,0.f,0.f};

  for (int k0 = 0; k0 < K; k0 += 32){
    __syncthreads();
    gl_lds16(pA0, lA0);
    gl_lds16(pA1, lA1);
    gl_lds16(pB0, lB0);
    gl_lds16(pB1, lB1);
    __syncthreads();
    s16x8 af[4], bfr[4];
    #pragma unroll
    for (int t=0;t<4;t++){
      af[t]  = *(const s16x8*)(As + (wr + t*16 + fr)*32 + fk);
      bfr[t] = *(const s16x8*)(Bs + (wc + t*16 + fr)*32 + fk);
    }
    #pragma unroll
    for (int mt=0;mt<4;mt++)
      #pragma unroll
      for (int nt=0;nt<4;nt++)
        acc[mt][nt] = MFMA16(af[mt], bfr[nt], acc[mt][nt]);
    pA0 += 32; pA1 += 32; pB0 += 32; pB1 += 32;
  }

  const int crow = tile_m + wr + ((lane>>4)<<2);
  const int ccol = tile_n + wc + (lane&15);
  if (BF16_OUT){
    ushort* C = (ushort*)Cv;
    #pragma unroll
    for (int mt=0;mt<4;mt++)
      #pragma unroll
      for (int r=0;r<4;r++){
        long row = crow + mt*16 + r;
        #pragma unroll
        for (int nt=0;nt<4;nt++)
          C[row*(long)N + ccol + nt*16] = f2bf(acc[mt][nt][r]);
      }
  } else {
    float* C = (float*)Cv;
    #pragma unroll
    for (int mt=0;mt<4;mt++)
      #pragma unroll
      for (int r=0;r<4;r++){
        long row = crow + mt*16 + r;
        #pragma unroll
        for (int nt=0;nt<4;nt++)
          C[row*(long)N + ccol + nt*16] = acc[mt][nt][r];
      }
  }
}

// ---------------- beta / log-decay epilogue from bapr[4096][128] ----------------
__global__ __launch_bounds__(256) void ba_post(const float* __restrict__ bapr,
    const float* __restrict__ dtb, const float* __restrict__ alog,
    float* __restrict__ beta, float* __restrict__ glog){
  const int idx = blockIdx.x*256 + threadIdx.x;     // over 4096*64
  const int m = idx >> 6, j = idx & 63;
  const float v = bapr[(long)m*128 + j];
  if (j < 32){
    beta[(long)m*32 + j] = 1.f/(1.f+expf(-v));
  } else {
    const int n = j - 32;
    float ap = v + dtb[n];
    float sp = (ap > 20.f) ? ap : log1pf(expf(ap));
    glog[(long)m*32 + n] = -expf(alog[n]) * sp;     // log decay g
  }
}

// ---------------- causal depthwise conv(K=4) + silu + l2norm(q,k) ----------------
__global__ __launch_bounds__(128) void conv_qkv(const ushort* __restrict__ mixed,
    const float* __restrict__ convw, ushort* __restrict__ qn, ushort* __restrict__ kn,
    ushort* __restrict__ vv){
  const int m = blockIdx.x;
  const int g = blockIdx.y;
  const int s = m & 2047;
  const int c = (g<<7) + threadIdx.x;
  float acc = 0.f;
  #pragma unroll
  for (int j=0;j<4;j++){
    int so = s - 3 + j;
    if (so >= 0) acc += bf2f(mixed[(long)(m-3+j)*8192 + c]) * convw[c*4+j];
  }
  float y = acc / (1.f + expf(-acc));
  if (g < 32){
    float ss = y*y;
    #pragma unroll
    for (int off=32; off; off>>=1) ss += __shfl_xor(ss, off);
    __shared__ float w2[2];
    if ((threadIdx.x&63)==0) w2[threadIdx.x>>6] = ss;
    __syncthreads();
    float r = rsqrtf(w2[0] + w2[1] + 1e-6f);
    if (g < 16) qn[(long)m*2048 + c]          = f2bf(y*r*0.08838834764831845f);
    else        kn[(long)m*2048 + (c-2048)]   = f2bf(y*r);
  } else {
    vv[(long)m*4096 + (c-4096)] = f2bf(y);
  }
}

// ---------------- pass 1: per-chunk T=(I+Ahat)^-1, M, cumLg (parallel, 4096 blocks) --------
__global__ __launch_bounds__(256) void chunk_prep(
    const ushort* __restrict__ qn, const ushort* __restrict__ kn,
    const float* __restrict__ beta, const float* __restrict__ glog,
    ushort* __restrict__ Tg, ushort* __restrict__ Mg, float* __restrict__ cumLgG){
  const int bid = blockIdx.x;
  const int bh = bid >> 6, ch = bid & 63;
  const int b = bh>>5, h = bh&31, hq = h>>1;
  const long tch = (long)b*2048 + ch*32;
  const int tid = threadIdx.x, w = tid>>6, lane = tid&63;
  const int quad = lane>>4, l15 = lane&15;

  __shared__ __attribute__((aligned(16))) ushort Kl[32][136];
  __shared__ __attribute__((aligned(16))) ushort Ql[32][136];
  __shared__ float Asl[32][33];
  __shared__ float Lgl[32], Btl[32];

  const int sc = tid>>3, ss = (tid&7)*16;
  {
    const ushort* kp = kn + (tch+sc)*2048 + hq*128 + ss;
    const ushort* qp = qn + (tch+sc)*2048 + hq*128 + ss;
    *(u32x4*)&Kl[sc][ss] = *(const u32x4*)kp; *(u32x4*)&Kl[sc][ss+8] = *(const u32x4*)(kp+8);
    *(u32x4*)&Ql[sc][ss] = *(const u32x4*)qp; *(u32x4*)&Ql[sc][ss+8] = *(const u32x4*)(qp+8);
  }
  if (tid < 64){
    const int c = lane & 31;
    float gv = glog[(tch + c)*32 + h];
    float bv = beta[(tch + c)*32 + h];
    #pragma unroll
    for (int off=1; off<32; off<<=1){
      float t = __shfl_up(gv, off);
      if ((lane & 31) >= off) gv += t;
    }
    if (lane < 32){ Lgl[c] = gv; Btl[c] = bv; cumLgG[(long)bid*32 + c] = gv; }
  }
  __syncthreads();

  const int mt = w>>1, nt = w&1;
  s16x8 ka[4], qa[4], kb[4];
  #pragma unroll
  for (int ks=0; ks<4; ks++){
    ka[ks] = *(const s16x8*)&Kl[mt*16+l15][ks*32 + quad*8];
    qa[ks] = *(const s16x8*)&Ql[mt*16+l15][ks*32 + quad*8];
    kb[ks] = *(const s16x8*)&Kl[nt*16+l15][ks*32 + quad*8];
  }
  f32x4 accK = (f32x4){0.f,0.f,0.f,0.f}, accQ = (f32x4){0.f,0.f,0.f,0.f};
  #pragma unroll
  for (int ks=0; ks<4; ks++){
    accK = MFMA16(ka[ks], kb[ks], accK);
    accQ = MFMA16(qa[ks], kb[ks], accQ);
  }
  const int j = nt*16 + l15;
  const float Lgj = Lgl[j];
  #pragma unroll
  for (int i=0;i<4;i++){
    const int r = mt*16 + quad*4 + i;
    const float e = expf(Lgl[r]-Lgj);
    Asl[r][j] = (r>j) ? -Btl[r]*e*accK[i] : 0.f;   // = -Ahat
    Mg[(long)bid*1024 + r*32 + j] = (r>=j) ? f2bf(e*accQ[i]) : (ushort)0;
  }
  __syncthreads();

  if (tid < 32){
    const int jc = tid;
    float tc[32];
    #pragma unroll
    for (int c=0;c<32;c++){
      float acc = (c==jc) ? 1.f : 0.f;
      #pragma unroll
      for (int i2=0;i2<c;i2++) acc = fmaf(Asl[c][i2], tc[i2], acc);
      tc[c] = acc;
      Tg[(long)bid*1024 + c*32 + jc] = f2bf(acc);
    }
  }
}

// ---------------- pass 2: sequential inter-chunk recurrence, MFMA only ----------------
__global__ __launch_bounds__(256) void chunk_scan2(
    const ushort* __restrict__ qn, const ushort* __restrict__ kn,
    const ushort* __restrict__ vv, const float* __restrict__ beta,
    const float* __restrict__ cumLg, const ushort* __restrict__ Tg,
    const ushort* __restrict__ Mg, float* __restrict__ o){
  const int bh = blockIdx.x & 63, sl = blockIdx.x >> 6;
  const int b = bh>>5, h = bh&31, hq = h>>1;
  const int dv0 = sl*32;
  const int tid = threadIdx.x, w = tid>>6, lane = tid&63;
  const int quad = lane>>4, l15 = lane&15;
  const int mtx = w>>1, ntx = w&1;
  const int sc = tid>>3, ss = (tid&7)*16;
  const int c0 = mtx*16 + quad*4;

  __shared__ __attribute__((aligned(16))) ushort STl[32][136];
  __shared__ __attribute__((aligned(16))) ushort KTl[128][40];
  __shared__ __attribute__((aligned(16))) ushort B0T[32][40];
  __shared__ __attribute__((aligned(16))) ushort DT[32][40];
  __shared__ float Lgc[32], Btf[32], eLgl[32], eDf[32];

  f32x4 S[2][2];
  #pragma unroll
  for (int i=0;i<2;i++)
    #pragma unroll
    for (int j2=0;j2<2;j2++) S[i][j2] = (f32x4){0.f,0.f,0.f,0.f};

  for (int ch=0; ch<64; ch++){
    const long tch = (long)b*2048 + ch*32;
    const long pb = (long)bh*64 + ch;
    if (tid < 32){
      float lg = cumLg[pb*32 + tid];
      float lgC = __shfl(lg, 31);
      Lgc[tid] = lg;
      Btf[tid] = beta[(tch + tid)*32 + h];
      eLgl[tid] = expf(lg);
      eDf[tid]  = expf(lgC - lg);
    }
    #pragma unroll
    for (int ti=0; ti<2; ti++){
      const int m0 = (2*w+ti)*16 + quad*4;
      #pragma unroll
      for (int nt=0; nt<2; nt++){
        const int n = nt*16 + l15;
        ushort4 pk;
        pk.x = f2bf(S[ti][nt][0]); pk.y = f2bf(S[ti][nt][1]);
        pk.z = f2bf(S[ti][nt][2]); pk.w = f2bf(S[ti][nt][3]);
        *(ushort4*)&STl[n][m0] = pk;
      }
    }
    {
      __attribute__((aligned(16))) ushort kv[16];
      const ushort* kp = kn + (tch+sc)*2048 + hq*128 + ss;
      *(u32x4*)&kv[0] = *(const u32x4*)kp;
      *(u32x4*)&kv[8] = *(const u32x4*)(kp+8);
      #pragma unroll
      for (int e=0;e<16;e++) KTl[ss+e][sc] = kv[e];
    }
    __syncthreads();

    f32x4 X = (f32x4){0.f,0.f,0.f,0.f}, Y = (f32x4){0.f,0.f,0.f,0.f};
    {
      const ushort* kA = kn + (tch + mtx*16 + l15)*2048 + hq*128 + quad*8;
      const ushort* qA = qn + (tch + mtx*16 + l15)*2048 + hq*128 + quad*8;
      #pragma unroll
      for (int ks=0; ks<4; ks++){
        s16x8 af = *(const s16x8*)(kA + ks*32);
        s16x8 qf = *(const s16x8*)(qA + ks*32);
        s16x8 sb = *(const s16x8*)&STl[ntx*16 + l15][ks*32 + quad*8];
        X = MFMA16(af, sb, X);
        Y = MFMA16(qf, sb, Y);
      }
    }
    #pragma unroll
    for (int i=0;i<4;i++){
      const int c = c0+i;
      float vval = bf2f(vv[(tch+c)*4096 + h*128 + dv0 + ntx*16 + l15]);
      float b0 = Btf[c]*(vval - eLgl[c]*X[i]);
      B0T[ntx*16 + l15][c] = f2bf(b0);
      Y[i] *= eLgl[c];
    }
    __syncthreads();

    {
      s16x8 a  = *(const s16x8*)&B0T[mtx*16 + l15][quad*8];
      s16x8 bT = *(const s16x8*)(Tg + pb*1024 + (ntx*16 + l15)*32 + quad*8);
      f32x4 Dt = MFMA16(a, bT, ((f32x4){0.f,0.f,0.f,0.f}));
      #pragma unroll
      for (int i=0;i<4;i++)
        DT[mtx*16 + quad*4 + i][ntx*16 + l15] = f2bf(Dt[i]);
    }
    __syncthreads();

    {
      s16x8 ma = *(const s16x8*)(Mg + pb*1024 + (mtx*16+l15)*32 + quad*8);
      s16x8 db = *(const s16x8*)&DT[ntx*16 + l15][quad*8];
      f32x4 O = MFMA16(ma, db, Y);
      #pragma unroll
      for (int i=0;i<4;i++)
        o[(tch + c0 + i)*4096 + h*128 + dv0 + ntx*16 + l15] = O[i];
    }
    {
      const float eC = eLgl[31];
      float ed[8];
      #pragma unroll
      for (int j2=0;j2<8;j2++) ed[j2] = eDf[quad*8+j2];
      s16x8 kta[2], dfr[2];
      #pragma unroll
      for (int ti=0; ti<2; ti++){
        s16x8 raw = *(const s16x8*)&KTl[(2*w+ti)*16 + l15][quad*8];
        s16x8 sca;
        #pragma unroll
        for (int j2=0;j2<8;j2++) sca[j2] = (short)f2bf(bf2f((ushort)raw[j2])*ed[j2]);
        kta[ti] = sca;
        dfr[ti] = *(const s16x8*)&DT[ti*16 + l15][quad*8];
      }
      #pragma unroll
      for (int ti=0; ti<2; ti++)
        #pragma unroll
        for (int nt=0; nt<2; nt++){
          f32x4 t;
          #pragma unroll
          for (int i=0;i<4;i++) t[i] = S[ti][nt][i]*eC;
          S[ti][nt] = MFMA16(kta[ti], dfr[nt], t);
        }
    }
    __syncthreads();
  }
}

// ---------------- RMSNorm(gated) + silu(z) gate, bf16 out ----------------
__global__ __launch_bounds__(128) void norm_gate(const float* __restrict__ o,
    const ushort* __restrict__ z, const float* __restrict__ normw,
    ushort* __restrict__ og){
  const long mh = blockIdx.x;
  const int d = threadIdx.x;
  float x = o[mh*128 + d];
  float ss = x*x;
  #pragma unroll
  for (int off=32; off; off>>=1) ss += __shfl_xor(ss, off);
  __shared__ float w2[2];
  if ((d&63)==0) w2[d>>6] = ss;
  __syncthreads();
  float r = rsqrtf((w2[0]+w2[1])*(1.f/128.f) + 1e-6f);
  float zz = bf2f(z[mh*128 + d]);
  float sil = zz / (1.f + expf(-zz));
  og[mh*128 + d] = f2bf(x*r*normw[d]*sil);
}

extern "C" void kernel_launch(void* const* d_in, const int* in_sizes, int n_in,
                              void* d_out, int out_size, void* d_ws, size_t ws_size,
                              hipStream_t stream){
  const float* hs    = (const float*)d_in[0];
  const float* Wqkv  = (const float*)d_in[1];
  const float* Wz    = (const float*)d_in[2];
  const float* Wb    = (const float*)d_in[3];
  const float* Wa    = (const float*)d_in[4];
  const float* convw = (const float*)d_in[5];
  const float* normw = (const float*)d_in[6];
  const float* Wout  = (const float*)d_in[7];
  const float* dtb   = (const float*)d_in[8];
  const float* alog  = (const float*)d_in[9];

  char* ws = (char*)d_ws;
  ushort* hsb   = (ushort*)(ws);                 // [0,16M)    hs bf16  -> later kn
  ushort* wqb   = (ushort*)(ws + (16l<<20));     // [16,48M)   Wqkv bf16 -> later v -> og
  ushort* wzb   = (ushort*)(ws + (48l<<20));     // [48,64M)   Wz bf16  -> later qn
  ushort* wob   = (ushort*)(ws + (64l<<20));     // [64,80M)   Wout bf16
  ushort* mixed = (ushort*)(ws + (80l<<20));     // [80,144M)  mixed bf16 -> later o_raw f32
  ushort* zb    = (ushort*)(ws + (144l<<20));    // [144,176M) z bf16
  float*  beta  = (float*)(ws + (176l<<20));     // 512K
  float*  cumLg = (float*)(ws + (176l<<20) + (512l<<10)); // 512K
  float*  glog  = (float*)(ws + (177l<<20));     // 512K
  ushort* Tg    = (ushort*)(ws + (178l<<20));    // [178,186M) T bf16
  ushort* Mg    = (ushort*)(ws + (186l<<20));    // [186,194M) M bf16
  ushort* wbab  = (ushort*)(ws + (194l<<20));    // [194,194.5M) W_ba bf16 [128][2048]
  float*  bapr  = (float*)(ws + (195l<<20));     // [195,197M) ba projection fp32 [4096][128]
  ushort* kn = hsb;  ushort* qn = wzb;  ushort* vvp = wqb;  ushort* og = wqb;
  float*  o_raw = (float*)mixed;

  cvt_bf16<<<8192,  256, 0, stream>>>(hs,   hsb);
  cvt_bf16<<<16384, 256, 0, stream>>>(Wqkv, wqb);
  cvt_bf16<<<8192,  256, 0, stream>>>(Wz,   wzb);
  cvt_bf16<<<8192,  256, 0, stream>>>(Wout, wob);
  cvt_bf16<<<64,    256, 0, stream>>>(Wb,   wbab);          // rows 0..31
  cvt_bf16<<<64,    256, 0, stream>>>(Wa,   wbab + 65536);  // rows 32..63 (64..127 garbage, unread)

  gemm_bt<1><<<32*64, 256, 0, stream>>>(hsb, wqb, (void*)mixed, 4096, 8192, 2048);
  gemm_bt<1><<<32*32, 256, 0, stream>>>(hsb, wzb, (void*)zb,    4096, 4096, 2048);
  gemm_bt<0><<<32*1,  256, 0, stream>>>(hsb, wbab, (void*)bapr, 4096, 128,  2048);
  ba_post<<<1024, 256, 0, stream>>>(bapr, dtb, alog, beta, glog);

  conv_qkv<<<dim3(4096,64), 128, 0, stream>>>(mixed, convw, qn, kn, vvp);
  chunk_prep<<<4096, 256, 0, stream>>>(qn, kn, beta, glog, Tg, Mg, cumLg);
  chunk_scan2<<<256, 256, 0, stream>>>(qn, kn, vvp, beta, cumLg, Tg, Mg, o_raw);
  norm_gate<<<131072, 128, 0, stream>>>(o_raw, zb, normw, og);

  gemm_bt<0><<<32*16, 256, 0, stream>>>(og, wob, d_out, 4096, 2048, 4096);
}